// Round 1
// baseline (249.640 us; speedup 1.0000x reference)
//
#include <hip/hip_runtime.h>
#include <hip/hip_bf16.h>
#include <cstdint>

using bf16x8 = __attribute__((ext_vector_type(8))) short;
using f32x4  = __attribute__((ext_vector_type(4))) float;

__device__ __forceinline__ short f2bf(float f) {
  unsigned u = __builtin_bit_cast(unsigned, f);
  u += 0x7fffu + ((u >> 16) & 1u);
  return (short)(u >> 16);
}

__device__ __forceinline__ unsigned pack2(float a, float b) {
  unsigned ua = __builtin_bit_cast(unsigned, a);
  ua += 0x7fffu + ((ua >> 16) & 1u);
  unsigned ub = __builtin_bit_cast(unsigned, b);
  ub += 0x7fffu + ((ub >> 16) & 1u);
  return (ua >> 16) | (ub & 0xffff0000u);
}

// ---------- transpose + f32->bf16 convert: dst[C][R] = src[R][C] ----------
__global__ __launch_bounds__(256) void transpose_to_bf16(const float* __restrict__ src,
                                                         short* __restrict__ dst,
                                                         int R, int C) {
  int idx = blockIdx.x * 256 + threadIdx.x;
  if (idx >= R * C) return;
  int c = idx / R;
  int r = idx - c * R;
  dst[(size_t)c * R + r] = f2bf(src[(size_t)r * C + c]);
}

// ---------- GEMM: C[M][N] = A[M][K] * Bt[N][K]^T ----------
// A_F32: A is f32 (converted to bf16 on stage); else bf16.
// OUT_F32: write f32 + bias; else write bf16.
template <int A_F32, int OUT_F32>
__global__ __launch_bounds__(256) void gemm_bt(const void* __restrict__ Ap,
                                               const short* __restrict__ Bt,
                                               void* __restrict__ Cp,
                                               const float* __restrict__ bias,
                                               int N, int K) {
  __shared__ short Al[128][40];
  __shared__ short Bl[128][40];

  const int tid  = threadIdx.x;
  const int lane = tid & 63;
  const int w    = tid >> 6;
  const int c16  = lane & 15;
  const int g    = lane >> 4;
  const int wm   = (w >> 1) * 64;
  const int wn   = (w & 1) * 64;
  const int m0   = blockIdx.x * 128;
  const int n0   = blockIdx.y * 128;

  const int srow = tid >> 1;        // 0..127
  const int scol = (tid & 1) * 16;  // 0 / 16

  f32x4 acc[4][4] = {};

  for (int k0 = 0; k0 < K; k0 += 32) {
    // stage A tile (128 x 32)
    if (A_F32) {
      const float* A  = (const float*)Ap;
      const float* ap = A + (size_t)(m0 + srow) * K + k0 + scol;
      float4 f0 = *(const float4*)(ap);
      float4 f1 = *(const float4*)(ap + 4);
      float4 f2 = *(const float4*)(ap + 8);
      float4 f3 = *(const float4*)(ap + 12);
      bf16x8 v0, v1;
      v0[0] = f2bf(f0.x); v0[1] = f2bf(f0.y); v0[2] = f2bf(f0.z); v0[3] = f2bf(f0.w);
      v0[4] = f2bf(f1.x); v0[5] = f2bf(f1.y); v0[6] = f2bf(f1.z); v0[7] = f2bf(f1.w);
      v1[0] = f2bf(f2.x); v1[1] = f2bf(f2.y); v1[2] = f2bf(f2.z); v1[3] = f2bf(f2.w);
      v1[4] = f2bf(f3.x); v1[5] = f2bf(f3.y); v1[6] = f2bf(f3.z); v1[7] = f2bf(f3.w);
      *(bf16x8*)&Al[srow][scol]     = v0;
      *(bf16x8*)&Al[srow][scol + 8] = v1;
    } else {
      const short* A  = (const short*)Ap;
      const short* ap = A + (size_t)(m0 + srow) * K + k0 + scol;
      *(bf16x8*)&Al[srow][scol]     = *(const bf16x8*)(ap);
      *(bf16x8*)&Al[srow][scol + 8] = *(const bf16x8*)(ap + 8);
    }
    // stage B tile (128 x 32) from Bt[N][K]
    {
      const short* bp = Bt + (size_t)(n0 + srow) * K + k0 + scol;
      *(bf16x8*)&Bl[srow][scol]     = *(const bf16x8*)(bp);
      *(bf16x8*)&Bl[srow][scol + 8] = *(const bf16x8*)(bp + 8);
    }
    __syncthreads();

    bf16x8 af[4], bfr[4];
    #pragma unroll
    for (int mt = 0; mt < 4; mt++)
      af[mt] = *(const bf16x8*)&Al[wm + mt * 16 + c16][g * 8];
    #pragma unroll
    for (int nt = 0; nt < 4; nt++)
      bfr[nt] = *(const bf16x8*)&Bl[wn + nt * 16 + c16][g * 8];
    #pragma unroll
    for (int mt = 0; mt < 4; mt++)
      #pragma unroll
      for (int nt = 0; nt < 4; nt++)
        acc[mt][nt] = __builtin_amdgcn_mfma_f32_16x16x32_bf16(af[mt], bfr[nt], acc[mt][nt], 0, 0, 0);
    __syncthreads();
  }

  // epilogue: D layout col = lane&15, row = (lane>>4)*4 + reg  (verified m89)
  #pragma unroll
  for (int mt = 0; mt < 4; mt++) {
    #pragma unroll
    for (int nt = 0; nt < 4; nt++) {
      const int row = m0 + wm + mt * 16 + g * 4;
      const int col = n0 + wn + nt * 16 + c16;
      if (OUT_F32) {
        float* C = (float*)Cp;
        const float bb = bias ? bias[col] : 0.f;
        #pragma unroll
        for (int r = 0; r < 4; r++)
          C[(size_t)(row + r) * N + col] = acc[mt][nt][r] + bb;
      } else {
        short* C = (short*)Cp;
        #pragma unroll
        for (int r = 0; r < 4; r++)
          C[(size_t)(row + r) * N + col] = f2bf(acc[mt][nt][r]);
      }
    }
  }
}

// ---------- attention: 1 block per (b, h, fr); n_sp=256, dh=64 ----------
__global__ __launch_bounds__(256) void attn_kernel(const short* __restrict__ qkv,
                                                   short* __restrict__ attn_out) {
  __shared__ short Klds[256][72];   // 36864 B, pad 8 -> 2-way (free)
  __shared__ short VT[64][264];     // 33792 B, V transposed
  __shared__ float Sl[64 * 260];    // 66560 B, aliased with P (bf16 [64][264])
  short* Pl = (short*)Sl;

  const int tid  = threadIdx.x;
  const int lane = tid & 63;
  const int w    = tid >> 6;
  const int c16  = lane & 15;
  const int g    = lane >> 4;

  const int bid = blockIdx.x;
  const int fr  = bid & 31;
  const int h   = (bid >> 5) & 7;
  const int bb  = bid >> 8;
  const size_t rowbase = (size_t)bb * 8192 + (size_t)fr * 256;
  const short* qb = qkv + rowbase * 1536 + h * 64;
  const short* kb = qb + 512;
  const short* vb = qb + 1024;

  // ---- stage K rows + V^T ----
  {
    const int j = tid & 127;
    if (tid < 128) {
      const short* v0 = vb + (size_t)(2 * j) * 1536;
      const short* v1 = v0 + 1536;
      #pragma unroll
      for (int d0 = 0; d0 < 64; d0 += 8) {
        bf16x8 a = *(const bf16x8*)(v0 + d0);
        bf16x8 b = *(const bf16x8*)(v1 + d0);
        #pragma unroll
        for (int e = 0; e < 8; e++) {
          unsigned pk = ((unsigned)(unsigned short)a[e]) |
                        (((unsigned)(unsigned short)b[e]) << 16);
          *(unsigned*)&VT[d0 + e][2 * j] = pk;
        }
      }
    } else {
      const short* k0p = kb + (size_t)(2 * j) * 1536;
      const short* k1p = k0p + 1536;
      #pragma unroll
      for (int d0 = 0; d0 < 64; d0 += 8) {
        *(bf16x8*)&Klds[2 * j][d0]     = *(const bf16x8*)(k0p + d0);
        *(bf16x8*)&Klds[2 * j + 1][d0] = *(const bf16x8*)(k1p + d0);
      }
    }
  }
  __syncthreads();

  for (int c = 0; c < 4; c++) {
    const int qr0 = c * 64 + w * 16;  // wave's 16 Q rows this chunk

    // ---- S = Q K^T (per-wave 16x256) ----
    bf16x8 aq[2];
    #pragma unroll
    for (int ks = 0; ks < 2; ks++)
      aq[ks] = *(const bf16x8*)(qb + (size_t)(qr0 + c16) * 1536 + ks * 32 + g * 8);
    f32x4 sacc[16] = {};
    #pragma unroll
    for (int ks = 0; ks < 2; ks++) {
      #pragma unroll
      for (int nt = 0; nt < 16; nt++) {
        bf16x8 bk = *(const bf16x8*)&Klds[nt * 16 + c16][ks * 32 + g * 8];
        sacc[nt] = __builtin_amdgcn_mfma_f32_16x16x32_bf16(aq[ks], bk, sacc[nt], 0, 0, 0);
      }
    }
    #pragma unroll
    for (int nt = 0; nt < 16; nt++)
      #pragma unroll
      for (int r = 0; r < 4; r++)
        Sl[(size_t)(w * 16 + g * 4 + r) * 260 + nt * 16 + c16] = sacc[nt][r];
    __syncthreads();  // B0: S visible

    // ---- softmax: 4 lanes per row, 64 cols each ----
    const int row  = w * 16 + (lane >> 2);
    const int part = lane & 3;
    const float* sp = &Sl[(size_t)row * 260 + part * 64];
    float4 sv[16];
    #pragma unroll
    for (int i = 0; i < 16; i++) sv[i] = *(const float4*)(sp + i * 4);
    float mx = -1e30f;
    #pragma unroll
    for (int i = 0; i < 16; i++) {
      sv[i].x *= 0.125f; sv[i].y *= 0.125f; sv[i].z *= 0.125f; sv[i].w *= 0.125f;
      mx = fmaxf(mx, fmaxf(fmaxf(sv[i].x, sv[i].y), fmaxf(sv[i].z, sv[i].w)));
    }
    mx = fmaxf(mx, __shfl_xor(mx, 1));
    mx = fmaxf(mx, __shfl_xor(mx, 2));
    float sum = 0.f;
    #pragma unroll
    for (int i = 0; i < 16; i++) {
      sv[i].x = __expf(sv[i].x - mx); sv[i].y = __expf(sv[i].y - mx);
      sv[i].z = __expf(sv[i].z - mx); sv[i].w = __expf(sv[i].w - mx);
      sum += sv[i].x + sv[i].y + sv[i].z + sv[i].w;
    }
    sum += __shfl_xor(sum, 1);
    sum += __shfl_xor(sum, 2);
    const float inv = 1.0f / sum;
    __syncthreads();  // B1: everyone done reading S before P overwrites it

    short* prow = &Pl[(size_t)row * 264 + part * 64];
    #pragma unroll
    for (int i = 0; i < 16; i++) {
      uint2 pk;
      pk.x = pack2(sv[i].x * inv, sv[i].y * inv);
      pk.y = pack2(sv[i].z * inv, sv[i].w * inv);
      *(uint2*)(prow + i * 4) = pk;
    }
    __syncthreads();  // B2: P complete before PV fragment reads

    // ---- O = P V (per-wave 16x64, K=256) ----
    f32x4 oacc[4] = {};
    #pragma unroll
    for (int ks = 0; ks < 8; ks++) {
      bf16x8 pa = *(const bf16x8*)&Pl[(size_t)(w * 16 + c16) * 264 + ks * 32 + g * 8];
      #pragma unroll
      for (int nt = 0; nt < 4; nt++) {
        bf16x8 bv = *(const bf16x8*)&VT[nt * 16 + c16][ks * 32 + g * 8];
        oacc[nt] = __builtin_amdgcn_mfma_f32_16x16x32_bf16(pa, bv, oacc[nt], 0, 0, 0);
      }
    }
    #pragma unroll
    for (int nt = 0; nt < 4; nt++)
      #pragma unroll
      for (int r = 0; r < 4; r++) {
        const int orow = qr0 + g * 4 + r;
        const int ocol = nt * 16 + c16;
        attn_out[(rowbase + orow) * 512 + h * 64 + ocol] = f2bf(oacc[nt][r]);
      }
    __syncthreads();  // B3: P reads done before next chunk's S writes
  }
}

extern "C" void kernel_launch(void* const* d_in, const int* in_sizes, int n_in,
                              void* d_out, int out_size, void* d_ws, size_t ws_size,
                              hipStream_t stream) {
  const float* x     = (const float*)d_in[0];  // [4*8192, 512]
  const float* w_qkv = (const float*)d_in[1];  // [512, 1536]
  const float* w_out = (const float*)d_in[2];  // [512, 512]
  const float* b_out = (const float*)d_in[3];  // [512]
  float* out = (float*)d_out;                  // [4*8192, 512] f32

  const int M = 32768, DIM = 512, NQKV = 1536;

  short* wqkvT = (short*)d_ws;                         // [1536][512]
  short* woutT = wqkvT + (size_t)NQKV * DIM;           // [512][512]
  short* qkvb  = woutT + (size_t)DIM * DIM;            // [32768][1536]
  short* attnb = qkvb + (size_t)M * NQKV;              // [32768][512]

  transpose_to_bf16<<<(DIM * NQKV + 255) / 256, 256, 0, stream>>>(w_qkv, wqkvT, DIM, NQKV);
  transpose_to_bf16<<<(DIM * DIM + 255) / 256, 256, 0, stream>>>(w_out, woutT, DIM, DIM);

  // qkv = x @ w_qkv   (A f32 on-stage convert, out bf16)
  gemm_bt<1, 0><<<dim3(M / 128, NQKV / 128), 256, 0, stream>>>(x, wqkvT, qkvb, nullptr, NQKV, DIM);

  // axial attention, 1024 blocks = b*h*f
  attn_kernel<<<1024, 256, 0, stream>>>(qkvb, attnb);

  // out = attn @ w_out + b_out  (A bf16, out f32 + bias)
  gemm_bt<0, 1><<<dim3(M / 128, DIM / 128), 256, 0, stream>>>(attnb, woutT, out, b_out, DIM, DIM);
}

// Round 2
// 229.488 us; speedup vs baseline: 1.0878x; 1.0878x over previous
//
#include <hip/hip_runtime.h>
#include <hip/hip_bf16.h>
#include <cstdint>

using bf16x8 = __attribute__((ext_vector_type(8))) short;
using f32x4  = __attribute__((ext_vector_type(4))) float;

typedef const __attribute__((address_space(1))) void* gas_ptr;
typedef __attribute__((address_space(3))) void* lds_ptr;

__device__ __forceinline__ short f2bf(float f) {
  unsigned u = __builtin_bit_cast(unsigned, f);
  u += 0x7fffu + ((u >> 16) & 1u);
  return (short)(u >> 16);
}

__device__ __forceinline__ unsigned pack2(float a, float b) {
  unsigned ua = __builtin_bit_cast(unsigned, a);
  ua += 0x7fffu + ((ua >> 16) & 1u);
  unsigned ub = __builtin_bit_cast(unsigned, b);
  ub += 0x7fffu + ((ub >> 16) & 1u);
  return (ua >> 16) | (ub & 0xffff0000u);
}

// ---------- f32 -> bf16 bulk convert (8 elems/thread) ----------
__global__ __launch_bounds__(256) void convert_bf16(const float* __restrict__ src,
                                                    short* __restrict__ dst, int n8) {
  int i = blockIdx.x * 256 + threadIdx.x;
  if (i >= n8) return;
  const float4* s = (const float4*)(src + (size_t)i * 8);
  float4 a = s[0], b = s[1];
  uint4 o;
  o.x = pack2(a.x, a.y); o.y = pack2(a.z, a.w);
  o.z = pack2(b.x, b.y); o.w = pack2(b.z, b.w);
  *(uint4*)(dst + (size_t)i * 8) = o;
}

// ---------- transpose + f32->bf16 convert: dst[C][R] = src[R][C] ----------
__global__ __launch_bounds__(256) void transpose_to_bf16(const float* __restrict__ src,
                                                         short* __restrict__ dst,
                                                         int R, int C) {
  int idx = blockIdx.x * 256 + threadIdx.x;
  if (idx >= R * C) return;
  int c = idx / R;
  int r = idx - c * R;
  dst[(size_t)c * R + r] = f2bf(src[(size_t)r * C + c]);
}

// ---------- GEMM (m97 structure): C[M][N] = A[M][K] * Bt[N][K]^T ----------
// 128x128 tile, BK=32, 4 waves, global_load_lds width-16 staging, linear LDS.
template <int OUT_F32>
__global__ __launch_bounds__(256) void gemm_bt(const short* __restrict__ A,
                                               const short* __restrict__ Bt,
                                               void* __restrict__ Cp,
                                               const float* __restrict__ bias,
                                               int Mt, int N, int K) {
  __shared__ short Al[128 * 32];
  __shared__ short Bl[128 * 32];

  const int tid  = threadIdx.x;
  const int lane = tid & 63;
  const int w    = tid >> 6;
  const int c16  = lane & 15;
  const int g    = lane >> 4;
  const int wm   = (w >> 1) * 64;
  const int wn   = (w & 1) * 64;

  // XCD-aware bijective swizzle (grid divisible by 8)
  const int nwg = gridDim.x;
  const int bid = blockIdx.x;
  const int swz = (bid & 7) * (nwg >> 3) + (bid >> 3);
  const int mtile = swz % Mt;
  const int ntile = swz / Mt;
  const int m0 = mtile * 128;
  const int n0 = ntile * 128;

  // staging: 8 chunks of 16 rows; wave w owns chunks w and w+4, 1024 B each
  const int rsub = lane >> 2;          // row within chunk
  const int ksub = (lane & 3) * 8;     // bf16 elems within row
  const short* gA0 = A  + (size_t)(m0 + w * 16 + rsub) * K + ksub;
  const short* gA1 = A  + (size_t)(m0 + (w + 4) * 16 + rsub) * K + ksub;
  const short* gB0 = Bt + (size_t)(n0 + w * 16 + rsub) * K + ksub;
  const short* gB1 = Bt + (size_t)(n0 + (w + 4) * 16 + rsub) * K + ksub;
  short* lA0 = Al + w * 512;
  short* lA1 = Al + (w + 4) * 512;
  short* lB0 = Bl + w * 512;
  short* lB1 = Bl + (w + 4) * 512;

  f32x4 acc[4][4] = {};

  for (int k0 = 0; k0 < K; k0 += 32) {
    __builtin_amdgcn_global_load_lds((gas_ptr)(gA0 + k0), (lds_ptr)lA0, 16, 0, 0);
    __builtin_amdgcn_global_load_lds((gas_ptr)(gA1 + k0), (lds_ptr)lA1, 16, 0, 0);
    __builtin_amdgcn_global_load_lds((gas_ptr)(gB0 + k0), (lds_ptr)lB0, 16, 0, 0);
    __builtin_amdgcn_global_load_lds((gas_ptr)(gB1 + k0), (lds_ptr)lB1, 16, 0, 0);
    __syncthreads();

    bf16x8 af[4], bfr[4];
    #pragma unroll
    for (int mt = 0; mt < 4; mt++)
      af[mt] = *(const bf16x8*)&Al[(wm + mt * 16 + c16) * 32 + g * 8];
    #pragma unroll
    for (int nt = 0; nt < 4; nt++)
      bfr[nt] = *(const bf16x8*)&Bl[(wn + nt * 16 + c16) * 32 + g * 8];
    #pragma unroll
    for (int mt = 0; mt < 4; mt++)
      #pragma unroll
      for (int nt = 0; nt < 4; nt++)
        acc[mt][nt] = __builtin_amdgcn_mfma_f32_16x16x32_bf16(af[mt], bfr[nt], acc[mt][nt], 0, 0, 0);
    __syncthreads();
  }

  #pragma unroll
  for (int mt = 0; mt < 4; mt++) {
    #pragma unroll
    for (int nt = 0; nt < 4; nt++) {
      const int row = m0 + wm + mt * 16 + g * 4;
      const int col = n0 + wn + nt * 16 + c16;
      if (OUT_F32) {
        float* C = (float*)Cp;
        const float bb = bias ? bias[col] : 0.f;
        #pragma unroll
        for (int r = 0; r < 4; r++)
          C[(size_t)(row + r) * N + col] = acc[mt][nt][r] + bb;
      } else {
        short* C = (short*)Cp;
        #pragma unroll
        for (int r = 0; r < 4; r++)
          C[(size_t)(row + r) * N + col] = f2bf(acc[mt][nt][r]);
      }
    }
  }
}

// ---------- attention: 1 block per (b, h, fr); n_sp=256, dh=64 ----------
// In-register softmax; P is wave-private in LDS -> zero barriers in chunk loop.
__global__ __launch_bounds__(256) void attn_kernel(const short* __restrict__ qkv,
                                                   short* __restrict__ attn_out) {
  __shared__ short Klds[256][72];   // 36864 B, pad 8 -> 2-way (free)
  __shared__ short VT[64][264];     // 33792 B, V transposed
  __shared__ short Pl[64 * 264];    // 33792 B, wave-private rows

  const int tid  = threadIdx.x;
  const int lane = tid & 63;
  const int w    = tid >> 6;
  const int c16  = lane & 15;
  const int g    = lane >> 4;

  const int bid = blockIdx.x;
  const int fr  = bid & 31;
  const int h   = (bid >> 5) & 7;
  const int bb  = bid >> 8;
  const size_t rowbase = (size_t)bb * 8192 + (size_t)fr * 256;
  const short* qb = qkv + rowbase * 1536 + h * 64;
  const short* kb = qb + 512;
  const short* vb = qb + 1024;

  // ---- stage K rows + V^T ----
  {
    const int j = tid & 127;
    if (tid < 128) {
      const short* v0 = vb + (size_t)(2 * j) * 1536;
      const short* v1 = v0 + 1536;
      #pragma unroll
      for (int d0 = 0; d0 < 64; d0 += 8) {
        bf16x8 a = *(const bf16x8*)(v0 + d0);
        bf16x8 b = *(const bf16x8*)(v1 + d0);
        #pragma unroll
        for (int e = 0; e < 8; e++) {
          unsigned pk = ((unsigned)(unsigned short)a[e]) |
                        (((unsigned)(unsigned short)b[e]) << 16);
          *(unsigned*)&VT[d0 + e][2 * j] = pk;
        }
      }
    } else {
      const short* k0p = kb + (size_t)(2 * j) * 1536;
      const short* k1p = k0p + 1536;
      #pragma unroll
      for (int d0 = 0; d0 < 64; d0 += 8) {
        *(bf16x8*)&Klds[2 * j][d0]     = *(const bf16x8*)(k0p + d0);
        *(bf16x8*)&Klds[2 * j + 1][d0] = *(const bf16x8*)(k1p + d0);
      }
    }
  }
  __syncthreads();

  for (int c = 0; c < 4; c++) {
    const int qr0 = c * 64 + w * 16;  // wave's 16 Q rows this chunk

    // ---- S = Q K^T (per-wave 16x256) ----
    bf16x8 aq[2];
    #pragma unroll
    for (int ks = 0; ks < 2; ks++)
      aq[ks] = *(const bf16x8*)(qb + (size_t)(qr0 + c16) * 1536 + ks * 32 + g * 8);
    f32x4 sacc[16] = {};
    #pragma unroll
    for (int ks = 0; ks < 2; ks++) {
      #pragma unroll
      for (int nt = 0; nt < 16; nt++) {
        bf16x8 bk = *(const bf16x8*)&Klds[nt * 16 + c16][ks * 32 + g * 8];
        sacc[nt] = __builtin_amdgcn_mfma_f32_16x16x32_bf16(aq[ks], bk, sacc[nt], 0, 0, 0);
      }
    }

    // ---- in-register softmax: row = w*16 + g*4 + r, cols = nt*16 + c16 ----
    // 16-lane group (fixed g) spans a row's 256 cols via nt x c16.
    float mx[4] = {-1e30f, -1e30f, -1e30f, -1e30f};
    #pragma unroll
    for (int nt = 0; nt < 16; nt++)
      #pragma unroll
      for (int r = 0; r < 4; r++)
        mx[r] = fmaxf(mx[r], sacc[nt][r]);
    #pragma unroll
    for (int r = 0; r < 4; r++) {
      mx[r] = fmaxf(mx[r], __shfl_xor(mx[r], 1));
      mx[r] = fmaxf(mx[r], __shfl_xor(mx[r], 2));
      mx[r] = fmaxf(mx[r], __shfl_xor(mx[r], 4));
      mx[r] = fmaxf(mx[r], __shfl_xor(mx[r], 8));
    }
    float sum[4] = {0.f, 0.f, 0.f, 0.f};
    #pragma unroll
    for (int nt = 0; nt < 16; nt++)
      #pragma unroll
      for (int r = 0; r < 4; r++) {
        float p = __expf((sacc[nt][r] - mx[r]) * 0.125f);
        sacc[nt][r] = p;
        sum[r] += p;
      }
    #pragma unroll
    for (int r = 0; r < 4; r++) {
      sum[r] += __shfl_xor(sum[r], 1);
      sum[r] += __shfl_xor(sum[r], 2);
      sum[r] += __shfl_xor(sum[r], 4);
      sum[r] += __shfl_xor(sum[r], 8);
    }
    float inv[4];
    #pragma unroll
    for (int r = 0; r < 4; r++) inv[r] = 1.0f / sum[r];

    // ---- P -> LDS (wave-private rows w*16..w*16+15) ----
    #pragma unroll
    for (int nt = 0; nt < 16; nt++)
      #pragma unroll
      for (int r = 0; r < 4; r++)
        Pl[(size_t)(w * 16 + g * 4 + r) * 264 + nt * 16 + c16] = f2bf(sacc[nt][r] * inv[r]);

    // same-wave DS ordering is in-order; fence stops compiler reordering
    asm volatile("" ::: "memory");

    // ---- O = P V (per-wave 16x64, K=256) ----
    f32x4 oacc[4] = {};
    #pragma unroll
    for (int ks = 0; ks < 8; ks++) {
      bf16x8 pa = *(const bf16x8*)&Pl[(size_t)(w * 16 + c16) * 264 + ks * 32 + g * 8];
      #pragma unroll
      for (int nt = 0; nt < 4; nt++) {
        bf16x8 bv = *(const bf16x8*)&VT[nt * 16 + c16][ks * 32 + g * 8];
        oacc[nt] = __builtin_amdgcn_mfma_f32_16x16x32_bf16(pa, bv, oacc[nt], 0, 0, 0);
      }
    }
    #pragma unroll
    for (int nt = 0; nt < 4; nt++)
      #pragma unroll
      for (int r = 0; r < 4; r++) {
        const int orow = qr0 + g * 4 + r;
        const int ocol = nt * 16 + c16;
        attn_out[(rowbase + orow) * 512 + h * 64 + ocol] = f2bf(oacc[nt][r]);
      }
    asm volatile("" ::: "memory");  // WAR: next chunk's P writes vs this chunk's P reads
  }
}

extern "C" void kernel_launch(void* const* d_in, const int* in_sizes, int n_in,
                              void* d_out, int out_size, void* d_ws, size_t ws_size,
                              hipStream_t stream) {
  const float* x     = (const float*)d_in[0];  // [4*8192, 512]
  const float* w_qkv = (const float*)d_in[1];  // [512, 1536]
  const float* w_out = (const float*)d_in[2];  // [512, 512]
  const float* b_out = (const float*)d_in[3];  // [512]
  float* out = (float*)d_out;                  // [4*8192, 512] f32

  const int M = 32768, DIM = 512, NQKV = 1536;

  short* wqkvT = (short*)d_ws;                         // [1536][512]
  short* woutT = wqkvT + (size_t)NQKV * DIM;           // [512][512]
  short* qkvb  = woutT + (size_t)DIM * DIM;            // [32768][1536]
  short* attnb = qkvb + (size_t)M * NQKV;              // [32768][512]
  short* xbf   = attnb;                                // aliased: xbf dead before attn writes

  transpose_to_bf16<<<(DIM * NQKV + 255) / 256, 256, 0, stream>>>(w_qkv, wqkvT, DIM, NQKV);
  transpose_to_bf16<<<(DIM * DIM + 255) / 256, 256, 0, stream>>>(w_out, woutT, DIM, DIM);
  convert_bf16<<<(M * DIM / 8 + 255) / 256, 256, 0, stream>>>(x, xbf, M * DIM / 8);

  // qkv = x @ w_qkv   (bf16 in, bf16 out)
  gemm_bt<0><<<(M / 128) * (NQKV / 128), 256, 0, stream>>>(xbf, wqkvT, qkvb, nullptr,
                                                           M / 128, NQKV, DIM);

  // axial attention, 1024 blocks = b*h*f  (overwrites attnb/xbf)
  attn_kernel<<<1024, 256, 0, stream>>>(qkvb, attnb);

  // out = attn @ w_out + b_out  (bf16 in, f32 + bias out)
  gemm_bt<1><<<(M / 128) * (DIM / 128), 256, 0, stream>>>(attnb, woutT, out, b_out,
                                                          M / 128, DIM, DIM);
}